// Round 8
// baseline (521.442 us; speedup 1.0000x reference)
//
#include <hip/hip_runtime.h>
#include <cstdint>
#include <cstddef>

// Problem constants
#define H_   4096
#define D_   1024
#define A_   512
#define B_   4
#define LQ_  2048
#define TM_  1500
#define TMP_ 1536   // TM padded to multiple of 128
#define EPS_ 1e-5f

typedef __attribute__((ext_vector_type(8))) _Float16 half8;
typedef __attribute__((ext_vector_type(4))) _Float16 half4v;
typedef __attribute__((ext_vector_type(4))) float f32x4;

// ---------------------------------------------------------------- helpers
__device__ __forceinline__ void gload_lds16(void* g, void* l) {
  // async global->LDS, 16B per lane; LDS dest = wave-uniform base + lane*16
  __builtin_amdgcn_global_load_lds((__attribute__((address_space(1))) void*)g,
                                   (__attribute__((address_space(3))) void*)l,
                                   16, 0, 0);
}

// ---------------------------------------------------------------- core 128x128 MFMA tile
// (m97-class structure; R2-frozen. Used by kv_kernel + scores_kernel.)
template <int OUTMODE>
__device__ __forceinline__ void gemm_tile(
    const _Float16* __restrict__ A, int lda,
    const _Float16* __restrict__ Bt, int ldb,
    const float* __restrict__ bias,
    void* __restrict__ C, int ldc,
    int Mvalid, int m0, int n0, int kbase, int kiters, float scale,
    _Float16* As, _Float16* Bs,
    const unsigned char* __restrict__ mrow, float* __restrict__ lsum, int nvalid) {
  const int tid = threadIdx.x;
  const int lane = tid & 63;
  const int wave = tid >> 6;

  f32x4 acc[4][4];
#pragma unroll
  for (int i = 0; i < 4; ++i)
#pragma unroll
    for (int jj = 0; jj < 4; ++jj) acc[i][jj] = (f32x4){0.f, 0.f, 0.f, 0.f};

  const _Float16* gA[2];
  const _Float16* gB[2];
  _Float16* lA[2];
  _Float16* lB[2];
#pragma unroll
  for (int i = 0; i < 2; ++i) {
    const int c = wave * 64 + lane + 256 * i;
    const int r = c >> 2;
    const int cs = c & 3;
    const int col = (cs ^ ((r >> 1) & 3)) * 8;  // XOR-swizzled 16B chunk
    int ra = m0 + r;
    if (ra >= Mvalid) ra = Mvalid - 1;  // clamp (pad rows dup last valid row)
    gA[i] = A + (size_t)ra * lda + kbase + col;
    gB[i] = Bt + (size_t)(n0 + r) * ldb + kbase + col;
    lA[i] = As + wave * 512 + i * 2048;
    lB[i] = Bs + wave * 512 + i * 2048;
  }

  const int wm = (wave >> 1) * 64;
  const int wn = (wave & 1) * 64;
  const int rsub = lane & 15;
  const int j = lane >> 4;
  const int slot = j ^ ((rsub >> 1) & 3);

  for (int kt = 0; kt < kiters; ++kt) {
    const int ko = kt * 32;
#pragma unroll
    for (int i = 0; i < 2; ++i) {
      gload_lds16((void*)(gA[i] + ko), (void*)lA[i]);
      gload_lds16((void*)(gB[i] + ko), (void*)lB[i]);
    }
    __syncthreads();
    half8 af[4], bfr[4];
#pragma unroll
    for (int x = 0; x < 4; ++x) {
      af[x]  = *(const half8*)&As[(wm + x * 16 + rsub) * 32 + slot * 8];
      bfr[x] = *(const half8*)&Bs[(wn + x * 16 + rsub) * 32 + slot * 8];
    }
#pragma unroll
    for (int mi = 0; mi < 4; ++mi)
#pragma unroll
      for (int ni = 0; ni < 4; ++ni)
        acc[mi][ni] = __builtin_amdgcn_mfma_f32_16x16x32_f16(af[mi], bfr[ni], acc[mi][ni], 0, 0, 0);
    __syncthreads();
  }

  const int cn = n0 + wn + rsub;
  const int rm = m0 + wm + j * 4;

  if (OUTMODE == 3) {
    bool ok[4];
#pragma unroll
    for (int ni = 0; ni < 4; ++ni) {
      const int n = cn + ni * 16;
      const int nc = n < nvalid ? n : nvalid - 1;
      ok[ni] = (n < nvalid) && (mrow[nc] == 0);
    }
#pragma unroll
    for (int mi = 0; mi < 4; ++mi) {
#pragma unroll
      for (int r = 0; r < 4; ++r) {
        const int m = rm + mi * 16 + r;
        float rowsum = 0.f;
#pragma unroll
        for (int ni = 0; ni < 4; ++ni) {
          const int n = cn + ni * 16;
          const float e = ok[ni] ? __expf(acc[mi][ni][r] * scale) : 0.f;
          ((_Float16*)C)[(size_t)m * ldc + n] = (_Float16)e;
          rowsum += e;
        }
#pragma unroll
        for (int d = 1; d < 16; d <<= 1) rowsum += __shfl_xor(rowsum, d);
        if (rsub == 0) atomicAdd(&lsum[m], rowsum);
      }
    }
    return;
  }

  if (OUTMODE == 1) {
#pragma unroll
    for (int ni = 0; ni < 4; ++ni) {
      const int n = cn + ni * 16;
      const float bi = bias ? bias[n] : 0.f;
#pragma unroll
      for (int mi = 0; mi < 4; ++mi) {
        half4v pk;
#pragma unroll
        for (int r = 0; r < 4; ++r) pk[r] = (_Float16)(acc[mi][ni][r] * scale + bi);
        *(half4v*)&((_Float16*)C)[(size_t)n * ldc + rm + mi * 16] = pk;
      }
    }
    return;
  }

#pragma unroll
  for (int ni = 0; ni < 4; ++ni) {
    const int n = cn + ni * 16;
    const float bi = (OUTMODE == 0 && bias) ? bias[n] : 0.f;
#pragma unroll
    for (int mi = 0; mi < 4; ++mi) {
#pragma unroll
      for (int r = 0; r < 4; ++r) {
        const int m = rm + mi * 16 + r;
        const float v = acc[mi][ni][r] * scale + bi;
        if (OUTMODE == 0) ((_Float16*)C)[(size_t)m * ldc + n] = (_Float16)v;
        else ((float*)C)[(size_t)m * ldc + n] = v;
      }
    }
  }
}

// ---------------------------------------------------------------- R7/R8: 8-phase 256x256 MFMA tile
// Ring-4 LDS K-half slots per operand (16KB each; A lds[0..32767], B +32768).
// Per K-half h: phase0 {stage A(h+2); ds_read A(mh=0)+B; barrier; prio1; 16
// MFMA; prio0; barrier}; phase1 {stage B(h+2); ds_read A(mh=1); vmcnt(4)
// [confirms slot h+1, leaves A/B(h+2) in flight]; barrier; prio1; 16 MFMA;
// prio0; barrier}. Raw s_barrier (no vmcnt(0) drain -- that drain is the m97
// ~20% stall). Tail drains vmcnt(0) once at h=NKH-2. HW-VERIFIED at NKH=16
// (R7 wo8 refcheck pass). OUTMODE: 0 = f16+bias, 2 = fp32 (no bias).
template <int OUTMODE>
__device__ __forceinline__ void mfma256_tile(
    const _Float16* __restrict__ Ag, int lda,
    const _Float16* __restrict__ Bg, int ldb,
    const float* __restrict__ bias,
    void* __restrict__ Cg, int ldc,
    int m0, int n0, int kbase, int nkh, _Float16* lds) {
  const int tid = threadIdx.x;
  const int lane = tid & 63;
  const int wave = tid >> 6;
  const int wr = wave >> 2;   // 0..1 over M
  const int wc = wave & 3;    // 0..3 over N

  const _Float16* srcA[2];
  const _Float16* srcB[2];
  _Float16* dstA[2];
  _Float16* dstB[2];
#pragma unroll
  for (int p = 0; p < 2; ++p) {
    const int c = p * 512 + tid;     // 0..1023 (half-tile = 1024 16B-chunks)
    const int r = c >> 2, cs = c & 3;
    const int col = (cs ^ ((r >> 1) & 3)) * 8;   // inverse chunk swizzle on src
    srcA[p] = Ag + (size_t)(m0 + r) * lda + kbase + col;
    srcB[p] = Bg + (size_t)(n0 + r) * ldb + kbase + col;
    dstA[p] = lds + (p * 512 + wave * 64) * 8;           // + slot*8192
    dstB[p] = lds + 32768 + (p * 512 + wave * 64) * 8;   // + slot*8192
  }

  const int rsub = lane & 15;
  const int j = lane >> 4;
  const int sc_ = j ^ ((rsub >> 1) & 3);

  f32x4 acc[8][4];
#pragma unroll
  for (int i = 0; i < 8; ++i)
#pragma unroll
    for (int n = 0; n < 4; ++n) acc[i][n] = (f32x4){0.f, 0.f, 0.f, 0.f};

  // prologue: stage K-halves 0,1; confirm half 0 (4 of 8 in flight remain)
#pragma unroll
  for (int p = 0; p < 2; ++p) gload_lds16((void*)(srcA[p]), (void*)(dstA[p]));
#pragma unroll
  for (int p = 0; p < 2; ++p) gload_lds16((void*)(srcB[p]), (void*)(dstB[p]));
#pragma unroll
  for (int p = 0; p < 2; ++p) gload_lds16((void*)(srcA[p] + 32), (void*)(dstA[p] + 8192));
#pragma unroll
  for (int p = 0; p < 2; ++p) gload_lds16((void*)(srcB[p] + 32), (void*)(dstB[p] + 8192));
  asm volatile("s_waitcnt vmcnt(4)" ::: "memory");
  __builtin_amdgcn_s_barrier();

  half8 bf[4];
  for (int h = 0; h < nkh; ++h) {
    const int sl = h & 3;
    const _Float16* Asl = lds + sl * 8192;
    const _Float16* Bsl = lds + 32768 + sl * 8192;
    // ---------------- phase (h,0): mh=0
    if (h + 2 < nkh) {
      const int s2 = (h + 2) & 3;
#pragma unroll
      for (int p = 0; p < 2; ++p)
        gload_lds16((void*)(srcA[p] + (h + 2) * 32), (void*)(dstA[p] + s2 * 8192));
    }
    half8 af[4];
#pragma unroll
    for (int x = 0; x < 4; ++x) {
      af[x] = *(const half8*)&Asl[(wr * 128 + x * 16 + rsub) * 32 + sc_ * 8];
      bf[x] = *(const half8*)&Bsl[(wc * 64 + x * 16 + rsub) * 32 + sc_ * 8];
    }
    __builtin_amdgcn_s_barrier();
    __builtin_amdgcn_s_setprio(1);
#pragma unroll
    for (int mi = 0; mi < 4; ++mi)
#pragma unroll
      for (int ni = 0; ni < 4; ++ni)
        acc[mi][ni] = __builtin_amdgcn_mfma_f32_16x16x32_f16(af[mi], bf[ni], acc[mi][ni], 0, 0, 0);
    __builtin_amdgcn_s_setprio(0);
    __builtin_amdgcn_s_barrier();
    // ---------------- phase (h,1): mh=1
    if (h + 2 < nkh) {
      const int s2 = (h + 2) & 3;
#pragma unroll
      for (int p = 0; p < 2; ++p)
        gload_lds16((void*)(srcB[p] + (h + 2) * 32), (void*)(dstB[p] + s2 * 8192));
    }
#pragma unroll
    for (int x = 0; x < 4; ++x)
      af[x] = *(const half8*)&Asl[(wr * 128 + 64 + x * 16 + rsub) * 32 + sc_ * 8];
    if (h < nkh - 2) {
      asm volatile("s_waitcnt vmcnt(4)" ::: "memory");   // slot h+1 confirmed
    } else if (h == nkh - 2) {
      asm volatile("s_waitcnt vmcnt(0)" ::: "memory");   // tail drain
    }
    __builtin_amdgcn_s_barrier();
    __builtin_amdgcn_s_setprio(1);
#pragma unroll
    for (int mi = 0; mi < 4; ++mi)
#pragma unroll
      for (int ni = 0; ni < 4; ++ni)
        acc[4 + mi][ni] = __builtin_amdgcn_mfma_f32_16x16x32_f16(af[mi], bf[ni], acc[4 + mi][ni], 0, 0, 0);
    __builtin_amdgcn_s_setprio(0);
    __builtin_amdgcn_s_barrier();
  }

  // epilogue (C/D map col=rsub, row=j*4+reg -- verified in gemm_tile + R7 wo8)
  const int cn0 = n0 + wc * 64 + rsub;
  const int rm0 = m0 + wr * 128 + j * 4;
#pragma unroll
  for (int ni = 0; ni < 4; ++ni) {
    const int n = cn0 + ni * 16;
    const float bi = (OUTMODE == 0) ? bias[n] : 0.f;
#pragma unroll
    for (int mh = 0; mh < 2; ++mh)
#pragma unroll
      for (int mi = 0; mi < 4; ++mi)
#pragma unroll
        for (int r = 0; r < 4; ++r) {
          const int m = rm0 + mh * 64 + mi * 16 + r;
          if (OUTMODE == 0)
            ((_Float16*)Cg)[(size_t)m * ldc + n] = (_Float16)(acc[mh * 4 + mi][ni][r] + bi);
          else
            ((float*)Cg)[(size_t)m * ldc + n] = acc[mh * 4 + mi][ni][r];
        }
  }
}

// ---------------------------------------------------------------- 8-phase kernel instantiations
// Wo: ctx[8192,512] @ WoT[4096,512]^T + bo -> f16 [8192,4096]. 512 tiles.
__global__ __launch_bounds__(512, 1) void wo8_kernel(
    const _Float16* __restrict__ Ag, const _Float16* __restrict__ Bg,
    const float* __restrict__ bias, _Float16* __restrict__ Cg) {
  __shared__ __align__(16) _Float16 lds[65536];
  int id = (int)blockIdx.x;
  id = (id & 7) * 64 + (id >> 3);    // 64 tiles/XCD
  const int by = id >> 4, bx = id & 15;
  mfma256_tile<0>(Ag, 512, Bg, 512, bias, (void*)Cg, 4096,
                  by * 256, bx * 256, 0, 16, lds);
}

// Q: hnorm[8192,4096] @ WqT[512,4096]^T -> fp32 partials, split-K x4.
// 256 blocks = 64 tiles x 4 K-slices (slice K=1024, NKH=32); exactly 1/CU.
__global__ __launch_bounds__(512, 1) void q8_kernel(
    const _Float16* __restrict__ hnorm, const _Float16* __restrict__ WqT,
    float* __restrict__ Qpart4) {
  __shared__ __align__(16) _Float16 lds[65536];
  int id = (int)blockIdx.x;
  id = (id & 7) * 32 + (id >> 3);    // 32 blocks/XCD
  const int slice = id >> 6;          // 0..3
  const int t2 = id & 63;
  const int by = t2 >> 1, bx = t2 & 1;
  mfma256_tile<2>(hnorm, 4096, WqT, 4096, nullptr,
                  (void*)(Qpart4 + (size_t)slice * 8192 * A_), A_,
                  by * 256, bx * 256, slice * 1024, 32, lds);
}

// PV: sc[b][2048,1536] @ VT[b][512,1536]^T -> fp32 partials, split-K x3.
// 192 blocks = 4 batches x 16 tiles x 3 K-slices (slice K=512, NKH=16).
// Partial layout identical to old gemm_nt<2> call (areduce untouched).
__global__ __launch_bounds__(512, 1) void pv8_kernel(
    const _Float16* __restrict__ sc, const _Float16* __restrict__ VT,
    float* __restrict__ Apart) {
  __shared__ __align__(16) _Float16 lds[65536];
  int id = (int)blockIdx.x;
  id = (id & 7) * 24 + (id >> 3);    // 24 blocks/XCD
  const int b = id / 48;
  const int rem = id % 48;
  const int slice = rem / 16;
  const int tile = rem % 16;
  const int by = tile >> 1, bx = tile & 1;
  mfma256_tile<2>(sc + (size_t)b * LQ_ * TMP_, TMP_,
                  VT + (size_t)b * A_ * TMP_, TMP_, nullptr,
                  (void*)(Apart + (size_t)slice * B_ * LQ_ * A_ + (size_t)b * LQ_ * A_), A_,
                  by * 256, bx * 256, slice * 512, 16, lds);
}

// ---------------------------------------------------------------- scores GEMM + fused exp/mask + row sums
__global__ __launch_bounds__(256) void scores_kernel(
    const _Float16* __restrict__ Qh, const _Float16* __restrict__ Kp,
    _Float16* __restrict__ sc, const unsigned char* __restrict__ mask,
    float* __restrict__ lsum) {
  __shared__ __align__(16) _Float16 As[4096];
  __shared__ __align__(16) _Float16 Bs[4096];
  const int nx = gridDim.x, ny = gridDim.y;  // (12, 16, 4)
  int id = (int)blockIdx.x + nx * ((int)blockIdx.y + ny * (int)blockIdx.z);
  const int tot = nx * ny * (int)gridDim.z;  // 768
  id = (id & 7) * (tot >> 3) + (id >> 3);
  const int bx = id % nx;
  const int by = (id / nx) % ny;
  const int b = id / (nx * ny);
  gemm_tile<3>(Qh + (size_t)b * LQ_ * A_, A_, Kp + (size_t)b * TMP_ * A_, A_, nullptr,
               (void*)(sc + (size_t)b * LQ_ * TMP_), TMP_, LQ_,
               by * 128, bx * 128, 0, 16, 0.044194173824159216f,
               As, Bs, mask + (size_t)b * TM_, lsum + (size_t)b * LQ_, TM_);
}

// ---------------------------------------------------------------- K + V projections (Q moved to q8_kernel)
// blocks 0..191: K, 192..383: V(transposed out); per-section XCD remap.
__global__ __launch_bounds__(256) void kv_kernel(
    const _Float16* __restrict__ memh, const _Float16* __restrict__ WkT,
    const float* __restrict__ bk, _Float16* __restrict__ Kp,
    const _Float16* __restrict__ WvT, const float* __restrict__ bv,
    _Float16* __restrict__ VT) {
  __shared__ __align__(16) _Float16 As[4096];
  __shared__ __align__(16) _Float16 Bs[4096];
  const int bid0 = blockIdx.x;
  if (bid0 < 192) {
    int t = bid0;
    t = (t & 7) * 24 + (t >> 3);
    const int nb = t & 3, mb = (t >> 2) % 12, b = t / 48;
    gemm_tile<0>(memh + (size_t)b * TM_ * D_, D_, WkT, D_, bk,
                 (void*)(Kp + (size_t)b * TMP_ * A_), A_,
                 TM_, mb * 128, nb * 128, 0, 32, 1.f, As, Bs,
                 nullptr, nullptr, 0);
  } else {
    int t = bid0 - 192;
    t = (t & 7) * 24 + (t >> 3);
    const int nb = t & 3, mb = (t >> 2) % 12, b = t / 48;
    gemm_tile<1>(memh + (size_t)b * TM_ * D_, D_, WvT, D_, bv,
                 (void*)(VT + (size_t)b * A_ * TMP_), TMP_,
                 TM_, mb * 128, nb * 128, 0, 32, 1.f, As, Bs,
                 nullptr, nullptr, 0);
  }
}

// ---------------------------------------------------------------- split-K reduces
// R8: Q partials now 4 slices. Blocks >= 4096 zero lsum (8192 floats).
__global__ __launch_bounds__(256) void qreduce_kernel(
    const float* __restrict__ p, const float* __restrict__ bias,
    _Float16* __restrict__ out, float* __restrict__ lsum) {
  const int bid = blockIdx.x;
  if (bid >= 4096) {
    lsum[(bid - 4096) * 256 + threadIdx.x] = 0.f;
    return;
  }
  const size_t S2 = (size_t)8192 * A_;
  const size_t i = ((size_t)bid * 256 + threadIdx.x) * 4;
  const float4 a = *(const float4*)(p + i);
  const float4 b = *(const float4*)(p + S2 + i);
  const float4 c = *(const float4*)(p + 2 * S2 + i);
  const float4 d = *(const float4*)(p + 3 * S2 + i);
  const float4 bi = *(const float4*)(bias + (i & (A_ - 1)));
  half4v o;
  o.x = (_Float16)(a.x + b.x + c.x + d.x + bi.x);
  o.y = (_Float16)(a.y + b.y + c.y + d.y + bi.y);
  o.z = (_Float16)(a.z + b.z + c.z + d.z + bi.z);
  o.w = (_Float16)(a.w + b.w + c.w + d.w + bi.w);
  *(half4v*)(out + i) = o;
}

__global__ __launch_bounds__(256) void areduce_kernel(
    const float* __restrict__ p, const float* __restrict__ lsum,
    _Float16* __restrict__ out) {
  const size_t S = (size_t)B_ * LQ_ * A_;
  const size_t i = ((size_t)blockIdx.x * 256 + threadIdx.x) * 4;
  const float4 a = *(const float4*)(p + i);
  const float4 b = *(const float4*)(p + S + i);
  const float4 c = *(const float4*)(p + 2 * S + i);
  const float inv = 1.f / lsum[i >> 9];
  half4v o;
  o.x = (_Float16)((a.x + b.x + c.x) * inv);
  o.y = (_Float16)((a.y + b.y + c.y) * inv);
  o.z = (_Float16)((a.z + b.z + c.z) * inv);
  o.w = (_Float16)((a.w + b.w + c.w) * inv);
  *(half4v*)(out + i) = o;
}

// ---------------------------------------------------------------- LN1
__global__ __launch_bounds__(256) void ln1_kernel(
    const float* __restrict__ hidden, const float* __restrict__ lnw,
    const float* __restrict__ lnb, _Float16* __restrict__ hnorm) {
  const int t = threadIdx.x;
  const int lane = t & 63;
  const int row = blockIdx.x * 4 + (t >> 6);
  const float* x = hidden + (size_t)row * H_;
  _Float16* y = hnorm + (size_t)row * H_;
  float4 v[16];
  float s = 0.f, ss = 0.f;
#pragma unroll
  for (int i = 0; i < 16; ++i) {
    v[i] = ((const float4*)x)[lane + 64 * i];
    s  += v[i].x + v[i].y + v[i].z + v[i].w;
    ss += v[i].x * v[i].x + v[i].y * v[i].y + v[i].z * v[i].z + v[i].w * v[i].w;
  }
#pragma unroll
  for (int off = 32; off; off >>= 1) { s += __shfl_xor(s, off); ss += __shfl_xor(ss, off); }
  const float mu = s * (1.f / H_);
  const float var = ss * (1.f / H_) - mu * mu;
  const float rstd = rsqrtf(var + EPS_);
#pragma unroll
  for (int i = 0; i < 16; ++i) {
    float4 wv4 = ((const float4*)lnw)[lane + 64 * i];
    float4 bv4 = ((const float4*)lnb)[lane + 64 * i];
    half4v o;
    o.x = (_Float16)((v[i].x - mu) * rstd * wv4.x + bv4.x);
    o.y = (_Float16)((v[i].y - mu) * rstd * wv4.y + bv4.y);
    o.z = (_Float16)((v[i].z - mu) * rstd * wv4.z + bv4.z);
    o.w = (_Float16)((v[i].w - mu) * rstd * wv4.w + bv4.w);
    ((half4v*)y)[lane + 64 * i] = o;
  }
}

// ---------------------------------------------------------------- misc prep
__global__ __launch_bounds__(256) void misc_kernel(
    const float* __restrict__ mem, _Float16* __restrict__ memh,
    const float* __restrict__ Wq, _Float16* __restrict__ WqT,
    const float* __restrict__ Wk, _Float16* __restrict__ WkT,
    const float* __restrict__ Wv, _Float16* __restrict__ WvT,
    const float* __restrict__ Wo, _Float16* __restrict__ WoT) {
  __shared__ float smem[32 * 33];
  int bid = blockIdx.x;
  const int t = threadIdx.x;
  if (bid < 1500) {  // ---- mem fp32 -> f16
    const size_t i = ((size_t)bid * 256 + t) * 4;
    float4 f = *(const float4*)(mem + i);
    half4v o;
    o.x = (_Float16)f.x; o.y = (_Float16)f.y; o.z = (_Float16)f.z; o.w = (_Float16)f.w;
    *(half4v*)(memh + i) = o;
    return;
  }
  bid -= 1500;
  // ---- weight transpose fp32 [R][C] -> f16 [C][R], half4v (8B) stores
  const float* src;
  _Float16* dst;
  int R, C;
  if (bid < 2048) { src = Wq; dst = WqT; R = 4096; C = 512; }
  else if (bid < 2048 + 512) { bid -= 2048; src = Wk; dst = WkT; R = 1024; C = 512; }
  else if (bid < 2048 + 1024) { bid -= 2048 + 512; src = Wv; dst = WvT; R = 1024; C = 512; }
  else { bid -= 2048 + 1024; src = Wo; dst = WoT; R = 512; C = 4096; }
  const int nbx = C / 32;
  const int bx = bid % nbx, by = bid / nbx;
  const int tx = t & 31, ty = t >> 5;
  const int c0 = bx * 32, r0 = by * 32;
#pragma unroll
  for (int i = 0; i < 32; i += 8)
    smem[(ty + i) * 33 + tx] = src[(size_t)(r0 + ty + i) * C + c0 + tx];
  __syncthreads();
  {
    const int q = t & 7, cc = t >> 3;
    half4v g;
#pragma unroll
    for (int e = 0; e < 4; ++e) g[e] = (_Float16)smem[(4 * q + e) * 33 + cc];
    *(half4v*)&dst[(size_t)(c0 + cc) * R + r0 + 4 * q] = g;
  }
}

// ---------------------------------------------------------------- LN2 + gate epilogue -> out (fp32)
__global__ __launch_bounds__(256) void ln2_gate_kernel(
    const float* __restrict__ hidden_, const _Float16* __restrict__ ctxh_,
    const float* __restrict__ w, const float* __restrict__ bvec,
    const float* __restrict__ gate_logit, float* __restrict__ out_) {
  const int row = blockIdx.x;
  const float* h = hidden_ + (size_t)row * H_;
  const _Float16* c = ctxh_ + (size_t)row * H_;
  float* o = out_ + (size_t)row * H_;
  const int t = threadIdx.x;
  float4 hv[4];
  float xv[16];
  float s = 0.f, ss = 0.f;
#pragma unroll
  for (int i = 0; i < 4; ++i) {
    hv[i] = ((const float4*)h)[t + 256 * i];
    half4v cv = ((const half4v*)c)[t + 256 * i];
    xv[4 * i + 0] = hv[i].x + (float)cv.x;
    xv[4 * i + 1] = hv[i].y + (float)cv.y;
    xv[4 * i + 2] = hv[i].z + (float)cv.z;
    xv[4 * i + 3] = hv[i].w + (float)cv.w;
    s  += xv[4 * i + 0] + xv[4 * i + 1] + xv[4 * i + 2] + xv[4 * i + 3];
    ss += xv[4 * i + 0] * xv[4 * i + 0] + xv[4 * i + 1] * xv[4 * i + 1] +
          xv[4 * i + 2] * xv[4 * i + 2] + xv[4 * i + 3] * xv[4 * i + 3];
  }
  __shared__ float red[2][4];
  const int lane = t & 63, wv = t >> 6;
#pragma unroll
  for (int off = 32; off; off >>= 1) { s += __shfl_down(s, off); ss += __shfl_down(ss, off); }
  if (lane == 0) { red[0][wv] = s; red[1][wv] = ss; }
  __syncthreads();
  s  = red[0][0] + red[0][1] + red[0][2] + red[0][3];
  ss = red[1][0] + red[1][1] + red[1][2] + red[1][3];
  const float mu = s * (1.f / H_);
  const float var = ss * (1.f / H_) - mu * mu;
  const float rstd = rsqrtf(var + EPS_);
  const float g = 1.f / (1.f + __expf(-gate_logit[0]));
#pragma unroll
  for (int i = 0; i < 4; ++i) {
    float4 wv4 = ((const float4*)w)[t + 256 * i];
    float4 bv4 = ((const float4*)bvec)[t + 256 * i];
    float4 ov;
    ov.x = hv[i].x + g * ((xv[4 * i + 0] - mu) * rstd * wv4.x + bv4.x - hv[i].x);
    ov.y = hv[i].y + g * ((xv[4 * i + 1] - mu) * rstd * wv4.y + bv4.y - hv[i].y);
    ov.z = hv[i].z + g * ((xv[4 * i + 2] - mu) * rstd * wv4.z + bv4.z - hv[i].z);
    ov.w = hv[i].w + g * ((xv[4 * i + 3] - mu) * rstd * wv4.w + bv4.w - hv[i].w);
    ((float4*)o)[t + 256 * i] = ov;
  }
}

// ---------------------------------------------------------------- launcher
extern "C" void kernel_launch(void* const* d_in, const int* in_sizes, int n_in,
                              void* d_out, int out_size, void* d_ws, size_t ws_size,
                              hipStream_t stream) {
  const float* hidden = (const float*)d_in[0];
  const float* mem    = (const float*)d_in[1];
  const unsigned char* mask = (const unsigned char*)d_in[2];
  const float* Wq = (const float*)d_in[3];
  const float* bq = (const float*)d_in[4];
  const float* Wk = (const float*)d_in[5];
  const float* bk = (const float*)d_in[6];
  const float* Wv = (const float*)d_in[7];
  const float* bv = (const float*)d_in[8];
  const float* Wo = (const float*)d_in[9];
  const float* bo = (const float*)d_in[10];
  const float* lnw1 = (const float*)d_in[11];
  const float* lnb1 = (const float*)d_in[12];
  const float* lnw2 = (const float*)d_in[13];
  const float* lnb2 = (const float*)d_in[14];
  const float* gate = (const float*)d_in[15];
  float* out = (float*)d_out;

  // workspace layout (f16 elements); ws = 512 MiB (fill kernel writes 524 MB)
  _Float16* p = (_Float16*)d_ws;
  _Float16* hnorm = p; p += (size_t)8192 * H_;        // 67.1 MB
  _Float16* Qh    = p; p += (size_t)8192 * A_;        // 8.4 MB
  _Float16* memh  = p; p += (size_t)6000 * D_;        // 12.3 MB
  _Float16* WqT   = p; p += (size_t)A_ * H_;          // [A][H]
  _Float16* WkT   = p; p += (size_t)A_ * D_;          // [A][D] (dead after kv -> lsum alias)
  _Float16* WvT   = p; p += (size_t)A_ * D_;
  _Float16* WoT   = p; p += (size_t)H_ * A_;          // [H][A]
  _Float16* Kp    = p; p += (size_t)B_ * TMP_ * A_;   // [B][1536][512]
  _Float16* VT    = p; p += (size_t)B_ * A_ * TMP_;   // [B][512][1536]
  _Float16* sc    = p; p += (size_t)B_ * LQ_ * TMP_;  // [B][2048][1536] exp-scores
  _Float16* ctx   = p; p += (size_t)8192 * A_;        // [8192][512]
  float* Qpart4   = (float*)p; p += (size_t)4 * 8192 * A_ * 2;  // 67.1 MB (4 slices fp32)
  // aliases (disjoint lifetimes):
  float* Apart = (float*)hnorm;   // 3 x 4 x 2048 x 512 fp32 = 50.3 MB <= 67.1 MB
  float* lsum  = (float*)WkT;     // 8192 fp32; WkT dead after kv; zeroed in qreduce

  // 1a. LN1
  ln1_kernel<<<2048, 256, 0, stream>>>(hidden, lnw1, lnb1, hnorm);
  // 1b. mem->f16 + 4 weight transposes
  misc_kernel<<<1500 + 2048 + 512 + 512 + 2048, 256, 0, stream>>>(
      mem, memh, Wq, WqT, Wk, WkT, Wv, WvT, Wo, WoT);
  // 2a. Q projection, 8-phase split-K x4 (256 blocks x 512 thr, 1/CU)
  q8_kernel<<<256, 512, 0, stream>>>(hnorm, WqT, Qpart4);
  // 2b. K + V projections (m97 structure, 384 blocks)
  kv_kernel<<<384, 256, 0, stream>>>(memh, WkT, bk, Kp, WvT, bv, VT);
  // 3. Q = sum 4 partials + bq -> f16; tail blocks zero lsum
  qreduce_kernel<<<4096 + 32, 256, 0, stream>>>(Qpart4, bq, Qh, lsum);
  // 4. exp-scores + row sums
  scores_kernel<<<dim3(12, 16, 4), 256, 0, stream>>>(Qh, Kp, sc, mask, lsum);
  // 5. ctx partials = exp-scores @ V, 8-phase split-K x3 (192 blocks x 512 thr)
  pv8_kernel<<<192, 512, 0, stream>>>(sc, VT, Apart);
  // 6. ctx = (sum partials) / lsum -> f16
  areduce_kernel<<<4096, 256, 0, stream>>>(Apart, lsum, ctx);
  // 7. ctx_h = ctx @ Wo + bo (8-phase, 512 blocks x 512 thr)
  wo8_kernel<<<512, 512, 0, stream>>>(ctx, WoT, bo, hnorm);
  // 8. out = hidden + g*(LN(hidden+ctx_h) - hidden)
  ln2_gate_kernel<<<8192, 256, 0, stream>>>(hidden, hnorm, lnw2, lnb2, gate, out);
}

// Round 9
// 488.306 us; speedup vs baseline: 1.0679x; 1.0679x over previous
//
#include <hip/hip_runtime.h>
#include <cstdint>
#include <cstddef>

// Problem constants
#define H_   4096
#define D_   1024
#define A_   512
#define B_   4
#define LQ_  2048
#define TM_  1500
#define TMP_ 1536   // TM padded to multiple of 128
#define EPS_ 1e-5f

typedef __attribute__((ext_vector_type(8))) _Float16 half8;
typedef __attribute__((ext_vector_type(4))) _Float16 half4v;
typedef __attribute__((ext_vector_type(4))) float f32x4;

// ---------------------------------------------------------------- helpers
__device__ __forceinline__ void gload_lds16(void* g, void* l) {
  // async global->LDS, 16B per lane; LDS dest = wave-uniform base + lane*16
  __builtin_amdgcn_global_load_lds((__attribute__((address_space(1))) void*)g,
                                   (__attribute__((address_space(3))) void*)l,
                                   16, 0, 0);
}

// ---------------------------------------------------------------- core 128x128 MFMA tile
// (m97-class structure; R2-frozen: single-buffered 16KB + XCD swizzle.)
// R8 lesson: 8-phase 256^2 template only pays at >=2 blocks/CU and with no
// added partial traffic (q8@1/CU + pv8@192 blocks were neutral/negative).
template <int OUTMODE>
__device__ __forceinline__ void gemm_tile(
    const _Float16* __restrict__ A, int lda,
    const _Float16* __restrict__ Bt, int ldb,
    const float* __restrict__ bias,
    void* __restrict__ C, int ldc,
    int Mvalid, int m0, int n0, int kbase, int kiters, float scale,
    _Float16* As, _Float16* Bs,
    const unsigned char* __restrict__ mrow, float* __restrict__ lsum, int nvalid) {
  const int tid = threadIdx.x;
  const int lane = tid & 63;
  const int wave = tid >> 6;

  f32x4 acc[4][4];
#pragma unroll
  for (int i = 0; i < 4; ++i)
#pragma unroll
    for (int jj = 0; jj < 4; ++jj) acc[i][jj] = (f32x4){0.f, 0.f, 0.f, 0.f};

  const _Float16* gA[2];
  const _Float16* gB[2];
  _Float16* lA[2];
  _Float16* lB[2];
#pragma unroll
  for (int i = 0; i < 2; ++i) {
    const int c = wave * 64 + lane + 256 * i;
    const int r = c >> 2;
    const int cs = c & 3;
    const int col = (cs ^ ((r >> 1) & 3)) * 8;  // XOR-swizzled 16B chunk
    int ra = m0 + r;
    if (ra >= Mvalid) ra = Mvalid - 1;  // clamp (pad rows dup last valid row)
    gA[i] = A + (size_t)ra * lda + kbase + col;
    gB[i] = Bt + (size_t)(n0 + r) * ldb + kbase + col;
    lA[i] = As + wave * 512 + i * 2048;
    lB[i] = Bs + wave * 512 + i * 2048;
  }

  const int wm = (wave >> 1) * 64;
  const int wn = (wave & 1) * 64;
  const int rsub = lane & 15;
  const int j = lane >> 4;
  const int slot = j ^ ((rsub >> 1) & 3);

  for (int kt = 0; kt < kiters; ++kt) {
    const int ko = kt * 32;
#pragma unroll
    for (int i = 0; i < 2; ++i) {
      gload_lds16((void*)(gA[i] + ko), (void*)lA[i]);
      gload_lds16((void*)(gB[i] + ko), (void*)lB[i]);
    }
    __syncthreads();
    half8 af[4], bfr[4];
#pragma unroll
    for (int x = 0; x < 4; ++x) {
      af[x]  = *(const half8*)&As[(wm + x * 16 + rsub) * 32 + slot * 8];
      bfr[x] = *(const half8*)&Bs[(wn + x * 16 + rsub) * 32 + slot * 8];
    }
#pragma unroll
    for (int mi = 0; mi < 4; ++mi)
#pragma unroll
      for (int ni = 0; ni < 4; ++ni)
        acc[mi][ni] = __builtin_amdgcn_mfma_f32_16x16x32_f16(af[mi], bfr[ni], acc[mi][ni], 0, 0, 0);
    __syncthreads();
  }

  const int cn = n0 + wn + rsub;
  const int rm = m0 + wm + j * 4;

  if (OUTMODE == 3) {
    bool ok[4];
#pragma unroll
    for (int ni = 0; ni < 4; ++ni) {
      const int n = cn + ni * 16;
      const int nc = n < nvalid ? n : nvalid - 1;
      ok[ni] = (n < nvalid) && (mrow[nc] == 0);
    }
#pragma unroll
    for (int mi = 0; mi < 4; ++mi) {
#pragma unroll
      for (int r = 0; r < 4; ++r) {
        const int m = rm + mi * 16 + r;
        float rowsum = 0.f;
#pragma unroll
        for (int ni = 0; ni < 4; ++ni) {
          const int n = cn + ni * 16;
          const float e = ok[ni] ? __expf(acc[mi][ni][r] * scale) : 0.f;
          ((_Float16*)C)[(size_t)m * ldc + n] = (_Float16)e;
          rowsum += e;
        }
#pragma unroll
        for (int d = 1; d < 16; d <<= 1) rowsum += __shfl_xor(rowsum, d);
        if (rsub == 0) atomicAdd(&lsum[m], rowsum);
      }
    }
    return;
  }

  if (OUTMODE == 1) {
#pragma unroll
    for (int ni = 0; ni < 4; ++ni) {
      const int n = cn + ni * 16;
      const float bi = bias ? bias[n] : 0.f;
#pragma unroll
      for (int mi = 0; mi < 4; ++mi) {
        half4v pk;
#pragma unroll
        for (int r = 0; r < 4; ++r) pk[r] = (_Float16)(acc[mi][ni][r] * scale + bi);
        *(half4v*)&((_Float16*)C)[(size_t)n * ldc + rm + mi * 16] = pk;
      }
    }
    return;
  }

#pragma unroll
  for (int ni = 0; ni < 4; ++ni) {
    const int n = cn + ni * 16;
    const float bi = (OUTMODE == 0 && bias) ? bias[n] : 0.f;
#pragma unroll
    for (int mi = 0; mi < 4; ++mi) {
#pragma unroll
      for (int r = 0; r < 4; ++r) {
        const int m = rm + mi * 16 + r;
        const float v = acc[mi][ni][r] * scale + bi;
        if (OUTMODE == 0) ((_Float16*)C)[(size_t)m * ldc + n] = (_Float16)v;
        else ((float*)C)[(size_t)m * ldc + n] = v;
      }
    }
  }
}

// ---------------------------------------------------------------- generic batched/split-K GEMM
template <int OUTMODE>
__global__ __launch_bounds__(256) void gemm_nt_kernel(
    const _Float16* __restrict__ Aall, size_t strideA, int lda,
    const _Float16* __restrict__ Btall, size_t strideB, int ldb,
    const float* __restrict__ bias,
    void* __restrict__ Call, size_t strideC, size_t strideS,
    int ldc, int Mvalid, int kiters, int nslices, int sliceK, float scale) {
  __shared__ __align__(16) _Float16 As[4096];
  __shared__ __align__(16) _Float16 Bs[4096];
  const int nx = gridDim.x, ny = gridDim.y;
  int id = (int)blockIdx.x + nx * ((int)blockIdx.y + ny * (int)blockIdx.z);
  const int tot = nx * ny * (int)gridDim.z;
  id = (id & 7) * (tot >> 3) + (id >> 3);
  const int bx = id % nx;
  const int by = (id / nx) % ny;
  const int bz = id / (nx * ny);
  const int batch = bz / nslices;
  const int slice = bz % nslices;
  const _Float16* A = Aall + (size_t)batch * strideA;
  const _Float16* Bt = Btall + (size_t)batch * strideB;
  char* C = (char*)Call + ((size_t)batch * strideC + (size_t)slice * strideS) *
                          (OUTMODE == 2 ? 4 : 2);
  gemm_tile<OUTMODE>(A, lda, Bt, ldb, bias, (void*)C, ldc, Mvalid,
                     by * 128, bx * 128, slice * sliceK, kiters,
                     scale, As, Bs, nullptr, nullptr, 0);
}

// ---------------------------------------------------------------- R7: 8-phase 256x256 MFMA tile (HW-verified)
// Ring-4 LDS K-half slots/operand; counted vmcnt(4), raw s_barrier, setprio.
// Verified refcheck-pass in R7 at 512 blocks (2/CU). Used ONLY for Wo.
template <int OUTMODE>
__device__ __forceinline__ void mfma256_tile(
    const _Float16* __restrict__ Ag, int lda,
    const _Float16* __restrict__ Bg, int ldb,
    const float* __restrict__ bias,
    void* __restrict__ Cg, int ldc,
    int m0, int n0, int kbase, int nkh, _Float16* lds) {
  const int tid = threadIdx.x;
  const int lane = tid & 63;
  const int wave = tid >> 6;
  const int wr = wave >> 2;
  const int wc = wave & 3;

  const _Float16* srcA[2];
  const _Float16* srcB[2];
  _Float16* dstA[2];
  _Float16* dstB[2];
#pragma unroll
  for (int p = 0; p < 2; ++p) {
    const int c = p * 512 + tid;
    const int r = c >> 2, cs = c & 3;
    const int col = (cs ^ ((r >> 1) & 3)) * 8;
    srcA[p] = Ag + (size_t)(m0 + r) * lda + kbase + col;
    srcB[p] = Bg + (size_t)(n0 + r) * ldb + kbase + col;
    dstA[p] = lds + (p * 512 + wave * 64) * 8;
    dstB[p] = lds + 32768 + (p * 512 + wave * 64) * 8;
  }

  const int rsub = lane & 15;
  const int j = lane >> 4;
  const int sc_ = j ^ ((rsub >> 1) & 3);

  f32x4 acc[8][4];
#pragma unroll
  for (int i = 0; i < 8; ++i)
#pragma unroll
    for (int n = 0; n < 4; ++n) acc[i][n] = (f32x4){0.f, 0.f, 0.f, 0.f};

#pragma unroll
  for (int p = 0; p < 2; ++p) gload_lds16((void*)(srcA[p]), (void*)(dstA[p]));
#pragma unroll
  for (int p = 0; p < 2; ++p) gload_lds16((void*)(srcB[p]), (void*)(dstB[p]));
#pragma unroll
  for (int p = 0; p < 2; ++p) gload_lds16((void*)(srcA[p] + 32), (void*)(dstA[p] + 8192));
#pragma unroll
  for (int p = 0; p < 2; ++p) gload_lds16((void*)(srcB[p] + 32), (void*)(dstB[p] + 8192));
  asm volatile("s_waitcnt vmcnt(4)" ::: "memory");
  __builtin_amdgcn_s_barrier();

  half8 bf[4];
  for (int h = 0; h < nkh; ++h) {
    const int sl = h & 3;
    const _Float16* Asl = lds + sl * 8192;
    const _Float16* Bsl = lds + 32768 + sl * 8192;
    if (h + 2 < nkh) {
      const int s2 = (h + 2) & 3;
#pragma unroll
      for (int p = 0; p < 2; ++p)
        gload_lds16((void*)(srcA[p] + (h + 2) * 32), (void*)(dstA[p] + s2 * 8192));
    }
    half8 af[4];
#pragma unroll
    for (int x = 0; x < 4; ++x) {
      af[x] = *(const half8*)&Asl[(wr * 128 + x * 16 + rsub) * 32 + sc_ * 8];
      bf[x] = *(const half8*)&Bsl[(wc * 64 + x * 16 + rsub) * 32 + sc_ * 8];
    }
    __builtin_amdgcn_s_barrier();
    __builtin_amdgcn_s_setprio(1);
#pragma unroll
    for (int mi = 0; mi < 4; ++mi)
#pragma unroll
      for (int ni = 0; ni < 4; ++ni)
        acc[mi][ni] = __builtin_amdgcn_mfma_f32_16x16x32_f16(af[mi], bf[ni], acc[mi][ni], 0, 0, 0);
    __builtin_amdgcn_s_setprio(0);
    __builtin_amdgcn_s_barrier();
    if (h + 2 < nkh) {
      const int s2 = (h + 2) & 3;
#pragma unroll
      for (int p = 0; p < 2; ++p)
        gload_lds16((void*)(srcB[p] + (h + 2) * 32), (void*)(dstB[p] + s2 * 8192));
    }
#pragma unroll
    for (int x = 0; x < 4; ++x)
      af[x] = *(const half8*)&Asl[(wr * 128 + 64 + x * 16 + rsub) * 32 + sc_ * 8];
    if (h < nkh - 2) {
      asm volatile("s_waitcnt vmcnt(4)" ::: "memory");
    } else if (h == nkh - 2) {
      asm volatile("s_waitcnt vmcnt(0)" ::: "memory");
    }
    __builtin_amdgcn_s_barrier();
    __builtin_amdgcn_s_setprio(1);
#pragma unroll
    for (int mi = 0; mi < 4; ++mi)
#pragma unroll
      for (int ni = 0; ni < 4; ++ni)
        acc[4 + mi][ni] = __builtin_amdgcn_mfma_f32_16x16x32_f16(af[mi], bf[ni], acc[4 + mi][ni], 0, 0, 0);
    __builtin_amdgcn_s_setprio(0);
    __builtin_amdgcn_s_barrier();
  }

  const int cn0 = n0 + wc * 64 + rsub;
  const int rm0 = m0 + wr * 128 + j * 4;
#pragma unroll
  for (int ni = 0; ni < 4; ++ni) {
    const int n = cn0 + ni * 16;
    const float bi = (OUTMODE == 0) ? bias[n] : 0.f;
#pragma unroll
    for (int mh = 0; mh < 2; ++mh)
#pragma unroll
      for (int mi = 0; mi < 4; ++mi)
#pragma unroll
        for (int r = 0; r < 4; ++r) {
          const int m = rm0 + mh * 64 + mi * 16 + r;
          if (OUTMODE == 0)
            ((_Float16*)Cg)[(size_t)m * ldc + n] = (_Float16)(acc[mh * 4 + mi][ni][r] + bi);
          else
            ((float*)Cg)[(size_t)m * ldc + n] = acc[mh * 4 + mi][ni][r];
        }
  }
}

// Wo: ctx[8192,512] @ WoT[4096,512]^T + bo -> f16 [8192,4096]. 512 blocks (2/CU).
__global__ __launch_bounds__(512, 1) void wo8_kernel(
    const _Float16* __restrict__ Ag, const _Float16* __restrict__ Bg,
    const float* __restrict__ bias, _Float16* __restrict__ Cg) {
  __shared__ __align__(16) _Float16 lds[65536];
  int id = (int)blockIdx.x;
  id = (id & 7) * 64 + (id >> 3);
  const int by = id >> 4, bx = id & 15;
  mfma256_tile<0>(Ag, 512, Bg, 512, bias, (void*)Cg, 4096,
                  by * 256, bx * 256, 0, 16, lds);
}

// ---------------------------------------------------------------- scores GEMM + fused exp/mask + row sums
__global__ __launch_bounds__(256) void scores_kernel(
    const _Float16* __restrict__ Qh, const _Float16* __restrict__ Kp,
    _Float16* __restrict__ sc, const unsigned char* __restrict__ mask,
    float* __restrict__ lsum) {
  __shared__ __align__(16) _Float16 As[4096];
  __shared__ __align__(16) _Float16 Bs[4096];
  const int nx = gridDim.x, ny = gridDim.y;  // (12, 16, 4)
  int id = (int)blockIdx.x + nx * ((int)blockIdx.y + ny * (int)blockIdx.z);
  const int tot = nx * ny * (int)gridDim.z;  // 768
  id = (id & 7) * (tot >> 3) + (id >> 3);
  const int bx = id % nx;
  const int by = (id / nx) % ny;
  const int b = id / (nx * ny);
  gemm_tile<3>(Qh + (size_t)b * LQ_ * A_, A_, Kp + (size_t)b * TMP_ * A_, A_, nullptr,
               (void*)(sc + (size_t)b * LQ_ * TMP_), TMP_, LQ_,
               by * 128, bx * 128, 0, 16, 0.044194173824159216f,
               As, Bs, mask + (size_t)b * TM_, lsum + (size_t)b * LQ_, TM_);
}

// ---------------------------------------------------------------- fused Q + K + V projections (R9)
// blocks 0..255: Q DIRECT (no split-K: full K=4096 in-register, f16+bias out
//   -- deletes 134 MB Qpart round-trip + the qreduce dispatch);
// 256..447: K; 448..639: V(transposed); 640..671: zero lsum (dedicated buf,
//   NOT aliasing WkT -- K blocks still read WkT concurrently).
__global__ __launch_bounds__(256) void qkv_kernel(
    const _Float16* __restrict__ hnorm, const _Float16* __restrict__ WqT,
    const float* __restrict__ bq, _Float16* __restrict__ Qh,
    const _Float16* __restrict__ memh, const _Float16* __restrict__ WkT,
    const float* __restrict__ bk, _Float16* __restrict__ Kp,
    const _Float16* __restrict__ WvT, const float* __restrict__ bv,
    _Float16* __restrict__ VT, float* __restrict__ lsum) {
  __shared__ __align__(16) _Float16 As[4096];
  __shared__ __align__(16) _Float16 Bs[4096];
  const int bid0 = blockIdx.x;
  if (bid0 < 256) {
    const int bid = ((bid0 & 7) << 5) | (bid0 >> 3);  // chunked: 32 blocks/XCD
    const int nb = bid & 3, mb = bid >> 2;            // 4 n-tiles x 64 m-tiles
    gemm_tile<0>(hnorm, H_, WqT, H_, bq,
                 (void*)Qh, A_,
                 8192, mb * 128, nb * 128, 0, 64, 1.f, As, Bs,
                 nullptr, nullptr, 0);
  } else if (bid0 < 448) {
    int t = bid0 - 256;
    t = (t & 7) * 24 + (t >> 3);                      // chunked: 24 blocks/XCD
    const int nb = t & 3, mb = (t >> 2) % 12, b = t / 48;
    gemm_tile<0>(memh + (size_t)b * TM_ * D_, D_, WkT, D_, bk,
                 (void*)(Kp + (size_t)b * TMP_ * A_), A_,
                 TM_, mb * 128, nb * 128, 0, 32, 1.f, As, Bs,
                 nullptr, nullptr, 0);
  } else if (bid0 < 640) {
    int t = bid0 - 448;
    t = (t & 7) * 24 + (t >> 3);
    const int nb = t & 3, mb = (t >> 2) % 12, b = t / 48;
    gemm_tile<1>(memh + (size_t)b * TM_ * D_, D_, WvT, D_, bv,
                 (void*)(VT + (size_t)b * A_ * TMP_), TMP_,
                 TM_, mb * 128, nb * 128, 0, 32, 1.f, As, Bs,
                 nullptr, nullptr, 0);
  } else {
    lsum[(bid0 - 640) * 256 + threadIdx.x] = 0.f;     // 8192 floats
  }
}

// ---------------------------------------------------------------- attn reduce
__global__ __launch_bounds__(256) void areduce_kernel(
    const float* __restrict__ p, const float* __restrict__ lsum,
    _Float16* __restrict__ out) {
  const size_t S = (size_t)B_ * LQ_ * A_;
  const size_t i = ((size_t)blockIdx.x * 256 + threadIdx.x) * 4;
  const float4 a = *(const float4*)(p + i);
  const float4 b = *(const float4*)(p + S + i);
  const float4 c = *(const float4*)(p + 2 * S + i);
  const float inv = 1.f / lsum[i >> 9];  // row = i / 512
  half4v o;
  o.x = (_Float16)((a.x + b.x + c.x) * inv);
  o.y = (_Float16)((a.y + b.y + c.y) * inv);
  o.z = (_Float16)((a.z + b.z + c.z) * inv);
  o.w = (_Float16)((a.w + b.w + c.w) * inv);
  *(half4v*)(out + i) = o;
}

// ---------------------------------------------------------------- LN1
__global__ __launch_bounds__(256) void ln1_kernel(
    const float* __restrict__ hidden, const float* __restrict__ lnw,
    const float* __restrict__ lnb, _Float16* __restrict__ hnorm) {
  const int t = threadIdx.x;
  const int lane = t & 63;
  const int row = blockIdx.x * 4 + (t >> 6);
  const float* x = hidden + (size_t)row * H_;
  _Float16* y = hnorm + (size_t)row * H_;
  float4 v[16];
  float s = 0.f, ss = 0.f;
#pragma unroll
  for (int i = 0; i < 16; ++i) {
    v[i] = ((const float4*)x)[lane + 64 * i];
    s  += v[i].x + v[i].y + v[i].z + v[i].w;
    ss += v[i].x * v[i].x + v[i].y * v[i].y + v[i].z * v[i].z + v[i].w * v[i].w;
  }
#pragma unroll
  for (int off = 32; off; off >>= 1) { s += __shfl_xor(s, off); ss += __shfl_xor(ss, off); }
  const float mu = s * (1.f / H_);
  const float var = ss * (1.f / H_) - mu * mu;
  const float rstd = rsqrtf(var + EPS_);
#pragma unroll
  for (int i = 0; i < 16; ++i) {
    float4 wv4 = ((const float4*)lnw)[lane + 64 * i];
    float4 bv4 = ((const float4*)lnb)[lane + 64 * i];
    half4v o;
    o.x = (_Float16)((v[i].x - mu) * rstd * wv4.x + bv4.x);
    o.y = (_Float16)((v[i].y - mu) * rstd * wv4.y + bv4.y);
    o.z = (_Float16)((v[i].z - mu) * rstd * wv4.z + bv4.z);
    o.w = (_Float16)((v[i].w - mu) * rstd * wv4.w + bv4.w);
    ((half4v*)y)[lane + 64 * i] = o;
  }
}

// ---------------------------------------------------------------- misc prep
__global__ __launch_bounds__(256) void misc_kernel(
    const float* __restrict__ mem, _Float16* __restrict__ memh,
    const float* __restrict__ Wq, _Float16* __restrict__ WqT,
    const float* __restrict__ Wk, _Float16* __restrict__ WkT,
    const float* __restrict__ Wv, _Float16* __restrict__ WvT,
    const float* __restrict__ Wo, _Float16* __restrict__ WoT) {
  __shared__ float smem[32 * 33];
  int bid = blockIdx.x;
  const int t = threadIdx.x;
  if (bid < 1500) {  // ---- mem fp32 -> f16
    const size_t i = ((size_t)bid * 256 + t) * 4;
    float4 f = *(const float4*)(mem + i);
    half4v o;
    o.x = (_Float16)f.x; o.y = (_Float16)f.y; o.z = (_Float16)f.z; o.w = (_Float16)f.w;
    *(half4v*)(memh + i) = o;
    return;
  }
  bid -= 1500;
  // ---- weight transpose fp32 [R][C] -> f16 [C][R], half4v (8B) stores
  const float* src;
  _Float16* dst;
  int R, C;
  if (bid < 2048) { src = Wq; dst = WqT; R = 4096; C = 512; }
  else if (bid < 2048 + 512) { bid -= 2048; src = Wk; dst = WkT; R = 1024; C = 512; }
  else if (bid < 2048 + 1024) { bid -= 2048 + 512; src = Wv; dst = WvT; R = 1024; C = 512; }
  else { bid -= 2048 + 1024; src = Wo; dst = WoT; R = 512; C = 4096; }
  const int nbx = C / 32;
  const int bx = bid % nbx, by = bid / nbx;
  const int tx = t & 31, ty = t >> 5;
  const int c0 = bx * 32, r0 = by * 32;
#pragma unroll
  for (int i = 0; i < 32; i += 8)
    smem[(ty + i) * 33 + tx] = src[(size_t)(r0 + ty + i) * C + c0 + tx];
  __syncthreads();
  {
    const int q = t & 7, cc = t >> 3;
    half4v g;
#pragma unroll
    for (int e = 0; e < 4; ++e) g[e] = (_Float16)smem[(4 * q + e) * 33 + cc];
    *(half4v*)&dst[(size_t)(c0 + cc) * R + r0 + 4 * q] = g;
  }
}

// ---------------------------------------------------------------- LN2 + gate epilogue -> out (fp32)
__global__ __launch_bounds__(256) void ln2_gate_kernel(
    const float* __restrict__ hidden_, const _Float16* __restrict__ ctxh_,
    const float* __restrict__ w, const float* __restrict__ bvec,
    const float* __restrict__ gate_logit, float* __restrict__ out_) {
  const int row = blockIdx.x;
  const float* h = hidden_ + (size_t)row * H_;
  const _Float16* c = ctxh_ + (size_t)row * H_;
  float* o = out_ + (size_t)row * H_;
  const int t = threadIdx.x;
  float4 hv[4];
  float xv[16];
  float s = 0.f, ss = 0.f;
#pragma unroll
  for (int i = 0; i < 4; ++i) {
    hv[i] = ((const float4*)h)[t + 256 * i];
    half4v cv = ((const half4v*)c)[t + 256 * i];
    xv[4 * i + 0] = hv[i].x + (float)cv.x;
    xv[4 * i + 1] = hv[i].y + (float)cv.y;
    xv[4 * i + 2] = hv[i].z + (float)cv.z;
    xv[4 * i + 3] = hv[i].w + (float)cv.w;
    s  += xv[4 * i + 0] + xv[4 * i + 1] + xv[4 * i + 2] + xv[4 * i + 3];
    ss += xv[4 * i + 0] * xv[4 * i + 0] + xv[4 * i + 1] * xv[4 * i + 1] +
          xv[4 * i + 2] * xv[4 * i + 2] + xv[4 * i + 3] * xv[4 * i + 3];
  }
  __shared__ float red[2][4];
  const int lane = t & 63, wv = t >> 6;
#pragma unroll
  for (int off = 32; off; off >>= 1) { s += __shfl_down(s, off); ss += __shfl_down(ss, off); }
  if (lane == 0) { red[0][wv] = s; red[1][wv] = ss; }
  __syncthreads();
  s  = red[0][0] + red[0][1] + red[0][2] + red[0][3];
  ss = red[1][0] + red[1][1] + red[1][2] + red[1][3];
  const float mu = s * (1.f / H_);
  const float var = ss * (1.f / H_) - mu * mu;
  const float rstd = rsqrtf(var + EPS_);
  const float g = 1.f / (1.f + __expf(-gate_logit[0]));
#pragma unroll
  for (int i = 0; i < 4; ++i) {
    float4 wv4 = ((const float4*)w)[t + 256 * i];
    float4 bv4 = ((const float4*)bvec)[t + 256 * i];
    float4 ov;
    ov.x = hv[i].x + g * ((xv[4 * i + 0] - mu) * rstd * wv4.x + bv4.x - hv[i].x);
    ov.y = hv[i].y + g * ((xv[4 * i + 1] - mu) * rstd * wv4.y + bv4.y - hv[i].y);
    ov.z = hv[i].z + g * ((xv[4 * i + 2] - mu) * rstd * wv4.z + bv4.z - hv[i].z);
    ov.w = hv[i].w + g * ((xv[4 * i + 3] - mu) * rstd * wv4.w + bv4.w - hv[i].w);
    ((float4*)o)[t + 256 * i] = ov;
  }
}

// ---------------------------------------------------------------- launcher
extern "C" void kernel_launch(void* const* d_in, const int* in_sizes, int n_in,
                              void* d_out, int out_size, void* d_ws, size_t ws_size,
                              hipStream_t stream) {
  const float* hidden = (const float*)d_in[0];
  const float* mem    = (const float*)d_in[1];
  const unsigned char* mask = (const unsigned char*)d_in[2];
  const float* Wq = (const float*)d_in[3];
  const float* bq = (const float*)d_in[4];
  const float* Wk = (const float*)d_in[5];
  const float* bk = (const float*)d_in[6];
  const float* Wv = (const float*)d_in[7];
  const float* bv = (const float*)d_in[8];
  const float* Wo = (const float*)d_in[9];
  const float* bo = (const float*)d_in[10];
  const float* lnw1 = (const float*)d_in[11];
  const float* lnb1 = (const float*)d_in[12];
  const float* lnw2 = (const float*)d_in[13];
  const float* lnb2 = (const float*)d_in[14];
  const float* gate = (const float*)d_in[15];
  float* out = (float*)d_out;

  // workspace layout (f16 elements)
  _Float16* p = (_Float16*)d_ws;
  _Float16* hnorm = p; p += (size_t)8192 * H_;        // 67.1 MB; later attn fp32 partials, then ctx_h
  _Float16* Qh    = p; p += (size_t)8192 * A_;        // 8.4 MB
  _Float16* memh  = p; p += (size_t)6000 * D_;        // 12.3 MB
  _Float16* WqT   = p; p += (size_t)A_ * H_;          // [A][H]
  _Float16* WkT   = p; p += (size_t)A_ * D_;          // [A][D]
  _Float16* WvT   = p; p += (size_t)A_ * D_;
  _Float16* WoT   = p; p += (size_t)H_ * A_;          // [H][A]
  _Float16* Kp    = p; p += (size_t)B_ * TMP_ * A_;   // [B][1536][512]
  _Float16* VT    = p; p += (size_t)B_ * A_ * TMP_;   // [B][512][1536]
  _Float16* sc    = p; p += (size_t)B_ * LQ_ * TMP_;  // [B][2048][1536] exp-scores
  _Float16* ctx   = p; p += (size_t)8192 * A_;        // [8192][512]
  float* lsum     = (float*)p; p += 8192 * 2;         // 32 KB, DEDICATED (R9: no WkT alias)
  // alias (disjoint lifetime): Apart over hnorm (dead between qkv and wo8)
  float* Apart = (float*)hnorm;   // 3 x 4 x 2048 x 512 fp32 = 50.3 MB <= 67.1 MB

  // 1a. LN1
  ln1_kernel<<<2048, 256, 0, stream>>>(hidden, lnw1, lnb1, hnorm);
  // 1b. mem->f16 + 4 weight transposes
  misc_kernel<<<1500 + 2048 + 512 + 512 + 2048, 256, 0, stream>>>(
      mem, memh, Wq, WqT, Wk, WkT, Wv, WvT, Wo, WoT);
  // 2. Q direct (256) + K (192) + V (192) + lsum zero (32): 672 blocks
  qkv_kernel<<<672, 256, 0, stream>>>(hnorm, WqT, bq, Qh,
                                      memh, WkT, bk, Kp, WvT, bv, VT, lsum);
  // 3. exp-scores + row sums
  scores_kernel<<<dim3(12, 16, 4), 256, 0, stream>>>(Qh, Kp, sc, mask, lsum);
  // 4. ctx partials = exp-scores @ V, split-K x3 (768 blocks, m97 structure)
  gemm_nt_kernel<2><<<dim3(4, 16, 12), 256, 0, stream>>>(
      sc, (size_t)LQ_ * TMP_, TMP_, VT, (size_t)A_ * TMP_, TMP_, nullptr,
      (void*)Apart, (size_t)LQ_ * A_, (size_t)B_ * LQ_ * A_, A_, LQ_, 16, 3, 512, 1.f);
  // 5. ctx = (sum partials) / lsum -> f16
  areduce_kernel<<<4096, 256, 0, stream>>>(Apart, lsum, ctx);
  // 6. ctx_h = ctx @ Wo + bo (8-phase, 512 blocks x 512 thr, R7-verified)
  wo8_kernel<<<512, 512, 0, stream>>>(ctx, WoT, bo, hnorm);
  // 7. out = hidden + g*(LN(hidden+ctx_h) - hidden)
  ln2_gate_kernel<<<8192, 256, 0, stream>>>(hidden, hnorm, lnw2, lnb2, gate, out);
}